// Round 4
// baseline (339643.164 us; speedup 1.0000x reference)
//
#include <hip/hip_runtime.h>

// RNNDetector: 2-layer LSTM (H=64), T=262144 sequential steps + 16-wide head.
// ROUND 14: R13 post-mortem showed the recurrence waves are BUBBLE-bound,
// not issue-bound (~380cyc issue vs ~1050cyc step; VALUBusy ~30%/wave).
// This round merges BOTH recurrences into ONE wave: per step it computes
// L0 step s and L1 step s-64 (block lag 2; wave1's xp/head roles and all
// ring lags unchanged). The two 128-fdot2 streams + activation chains are
// independent, so each chain's LDS/dep latency hides under the other's
// issue. 2-wave workgroup:
//   w0: L0(block k) + L1(block k-2) interleaved, in-lane, self-deps via
//       own LDS rings (in-order DS pipe, no barrier).
//   w1: xp1 = Wih1*h0 + b for block k-1; head out for block k-3.
// Also: negated exp2-prescale (weights carry -log2e / -2log2e) kills the
// negate+clamp ops in every sigmoid (overflow-safe both sides); tanh keeps
// one fminf NaN guard. ~370 actual VGPRs on w0 (<450 no-spill bound).

constexpr int T  = 262144;
constexpr int B  = 32;          // steps per superstep
constexpr int NB = T / B;       // 8192 blocks
constexpr int RS = 2 * B;       // 64 ring slots (2 blocks)
constexpr int K_SS = NB + 3;    // supersteps incl. pipeline drain

typedef _Float16 h2v __attribute__((ext_vector_type(2)));
typedef unsigned u4 __attribute__((ext_vector_type(4)));
typedef float    f4 __attribute__((ext_vector_type(4)));

struct TT { static constexpr bool value = true; };
struct FF { static constexpr bool value = false; };

__device__ __forceinline__ float rcp_f(float x) { return __builtin_amdgcn_rcpf(x); }

#define BARRIER() asm volatile("s_waitcnt lgkmcnt(0)\n\ts_barrier" ::: "memory")

// packed-f16 dot2: acc += w.lo*h.lo + w.hi*h.hi (f32 accumulate)
static __device__ __forceinline__ float fd(unsigned w, unsigned h, float acc) {
#if __has_builtin(__builtin_amdgcn_fdot2)
  return __builtin_amdgcn_fdot2(__builtin_bit_cast(h2v, w),
                                __builtin_bit_cast(h2v, h), acc, false);
#else
  h2v a = __builtin_bit_cast(h2v, w), b = __builtin_bit_cast(h2v, h);
  acc = fmaf((float)a.x, (float)b.x, acc);
  acc = fmaf((float)a.y, (float)b.y, acc);
  return acc;
#endif
}

#define DP4(acc, W, H) { acc = fd((W).x, (H).x, acc); acc = fd((W).y, (H).y, acc); \
                         acc = fd((W).z, (H).z, acc); acc = fd((W).w, (H).w, acc); }

// quad_perm DPP cross-lane (pure VALU, no LDS): xor1 = 0xB1, xor2 = 0x4E
#define DPPX1(x) __builtin_bit_cast(float, __builtin_amdgcn_mov_dpp(            \
                    __builtin_bit_cast(int, (x)), 0xB1, 0xF, 0xF, true))
#define DPPX2(x) __builtin_bit_cast(float, __builtin_amdgcn_mov_dpp(            \
                    __builtin_bit_cast(int, (x)), 0x4E, 0xF, 0xF, true))

// raw v_exp_f32 (2^x)
__device__ __forceinline__ float exp2_f(float x) {
  float r; asm("v_exp_f32 %0, %1" : "=v"(r) : "v"(x)); return r;
}
// un = -log2e * x  ->  sigmoid(x). Overflow-safe both sides:
// un=+big -> e=Inf -> rcp(Inf)=0; un=-big -> e=0 -> 1.
__device__ __forceinline__ float sig_n(float un) {
  return rcp_f(1.f + exp2_f(un));
}
// un = -2log2e * z  ->  tanh(z). Guard un<=126 (un=+Inf side would NaN).
__device__ __forceinline__ float tanh_n(float un) {
  float e2 = exp2_f(fminf(un, 126.f));
  return (1.f - e2) * rcp_f(1.f + e2);
}
// real-unit tanh (for cell state)
__device__ __forceinline__ float tanh_cn(float c) {
  return tanh_n(c * -2.8853900817779268f);
}

constexpr float L2E  = 1.4426950408889634f;
constexpr float L2E2 = 2.8853900817779268f;

// f32 -> f16 RNE (|w| < ~2 after prescale: no overflow; flush sub-6e-5 to 0)
__device__ unsigned f16rne(float f) {
  unsigned u = __float_as_uint(f);
  unsigned s = (u >> 16) & 0x8000u;
  int e = (int)((u >> 23) & 0xff) - 127;
  unsigned m = u & 0x7fffffu;
  if (e < -14) return s;
  unsigned h = s | (unsigned)((e + 15) << 10) | (m >> 13);
  unsigned rem = m & 0x1fffu;
  h += (rem > 0x1000u) || (rem == 0x1000u && (h & 1u));
  return h;
}

// ---- prepass: pack f16 weights, per-lane-contiguous, NEGATED exp2-prescale --
// All three 256x64 matrices share one layout: lane l, dword d (0..127):
//   r = d>>5 (gate i/f/g/o), kp = d&31, row = r*64+l, cols (2kp, 2kp+1).
//   scale = -2log2e for gate g (r==2), -log2e otherwise.
// region A [    0, 8192): Whh0  (w0, L0)
// region B [ 8192,16384): Whh1  (w0, L1)
// region C [16384,24576): Wih1  (w1, xp)
// region E [24576,25088): head: lane l (m=l>>2,kq=l&3), d=0..7:
//   Wlin[m][kq*16+2d], +1  (unscaled, positive)
__global__ void pack_w(const float* __restrict__ Whh0,
                       const float* __restrict__ Whh1,
                       const float* __restrict__ Wih1,
                       const float* __restrict__ Wlin,
                       unsigned* __restrict__ ws) {
  int i = blockIdx.x * 256 + threadIdx.x;
  if (i >= 25088) return;
  float v0, v1, sc = 1.f;
  if (i < 24576) {
    int w = i >> 13, rem = i & 8191, l = rem >> 7, d = rem & 127;
    int r = d >> 5, kp = d & 31, row = r * 64 + l;
    const float* src = (w == 0) ? Whh0 : (w == 1) ? Whh1 : Wih1;
    v0 = src[row * 64 + 2 * kp]; v1 = src[row * 64 + 2 * kp + 1];
    sc = (r == 2) ? -L2E2 : -L2E;
  } else {
    int j = i - 24576, l = j >> 3, d = j & 7;
    int m = l >> 2, kq = l & 3, k = kq * 16 + 2 * d;
    v0 = Wlin[m * 64 + k]; v1 = Wlin[m * 64 + k + 1];
  }
  ws[i] = f16rne(v0 * sc) | (f16rne(v1 * sc) << 16);
}

#define DECLW32(wp)                                                            \
  u4 W0=(wp)[0],  W1=(wp)[1],  W2=(wp)[2],  W3=(wp)[3],                        \
     W4=(wp)[4],  W5=(wp)[5],  W6=(wp)[6],  W7=(wp)[7],                        \
     W8=(wp)[8],  W9=(wp)[9],  W10=(wp)[10],W11=(wp)[11],                      \
     W12=(wp)[12],W13=(wp)[13],W14=(wp)[14],W15=(wp)[15],                      \
     W16=(wp)[16],W17=(wp)[17],W18=(wp)[18],W19=(wp)[19],                      \
     W20=(wp)[20],W21=(wp)[21],W22=(wp)[22],W23=(wp)[23],                      \
     W24=(wp)[24],W25=(wp)[25],W26=(wp)[26],W27=(wp)[27],                      \
     W28=(wp)[28],W29=(wp)[29],W30=(wp)[30],W31=(wp)[31]

#define DECLX32(wp)                                                            \
  u4 X0=(wp)[0],  X1=(wp)[1],  X2=(wp)[2],  X3=(wp)[3],                        \
     X4=(wp)[4],  X5=(wp)[5],  X6=(wp)[6],  X7=(wp)[7],                        \
     X8=(wp)[8],  X9=(wp)[9],  X10=(wp)[10],X11=(wp)[11],                      \
     X12=(wp)[12],X13=(wp)[13],X14=(wp)[14],X15=(wp)[15],                      \
     X16=(wp)[16],X17=(wp)[17],X18=(wp)[18],X19=(wp)[19],                      \
     X20=(wp)[20],X21=(wp)[21],X22=(wp)[22],X23=(wp)[23],                      \
     X24=(wp)[24],X25=(wp)[25],X26=(wp)[26],X27=(wp)[27],                      \
     X28=(wp)[28],X29=(wp)[29],X30=(wp)[30],X31=(wp)[31]

#define PINW8(a,b,c,d,e,f,g,h)                                                 \
  asm volatile("" : "+v"(a), "+v"(b), "+v"(c), "+v"(d),                        \
                    "+v"(e), "+v"(f), "+v"(g), "+v"(h))
#define PINALLW() { PINW8(W0,W1,W2,W3,W4,W5,W6,W7);                            \
                    PINW8(W8,W9,W10,W11,W12,W13,W14,W15);                      \
                    PINW8(W16,W17,W18,W19,W20,W21,W22,W23);                    \
                    PINW8(W24,W25,W26,W27,W28,W29,W30,W31); }
#define PINALLX() { PINW8(X0,X1,X2,X3,X4,X5,X6,X7);                            \
                    PINW8(X8,X9,X10,X11,X12,X13,X14,X15);                      \
                    PINW8(X16,X17,X18,X19,X20,X21,X22,X23);                    \
                    PINW8(X24,X25,X26,X27,X28,X29,X30,X31); }

__global__ __launch_bounds__(128)
__attribute__((amdgpu_waves_per_eu(1, 1)))
void rnn_fused(
    const float* __restrict__ y,
    const float* __restrict__ Wih0, const float* __restrict__ bih0,
    const float* __restrict__ bhh0,
    const float* __restrict__ bih1, const float* __restrict__ bhh1,
    const float* __restrict__ blin,
    const unsigned* __restrict__ ws,
    float* __restrict__ out)
{
  const int tid = threadIdx.x;
  // rings: block j occupies slots [j*B .. j*B+B) & (RS-1) — adjacent blocks
  // land in disjoint halves; all cross-wave same-slot reuse >= 1 barrier apart.
  __shared__ __align__(16) unsigned h0r[RS * 32];   // h0 f16, 8 KB
  __shared__ __align__(16) unsigned h1r[RS * 32];   // h1 f16, 8 KB
  __shared__ __align__(16) float    xpf[RS * 256];  // xp1 f32 elem-major, 64 KB

  for (int j = tid; j < RS * 32; j += 128) { h0r[j] = 0u; h1r[j] = 0u; }
  __syncthreads();

  if (tid < 64) {
    // ===== wave0: L0 (block k) + L1 (block k-2) interleaved, in-lane ======
    __builtin_amdgcn_s_setprio(1);
    const int e = tid;
    const u4* wpA = (const u4*)(ws + e * 128);          // Whh0 (negated-scaled)
    const u4* wpB = (const u4*)(ws + 8192 + e * 128);   // Whh1 (negated-scaled)
    DECLW32(wpA);
    DECLX32(wpB);
    float bbi = -(bih0[e] + bhh0[e]) * L2E;
    float bbf = -(bih0[64 + e] + bhh0[64 + e]) * L2E;
    float bbg = -(bih0[128 + e] + bhh0[128 + e]) * L2E2;
    float bbo = -(bih0[192 + e] + bhh0[192 + e]) * L2E;
    float wii = -Wih0[e] * L2E, wif = -Wih0[64 + e] * L2E;
    float wig = -Wih0[128 + e] * L2E2, wio = -Wih0[192 + e] * L2E;
    float c0 = 0.f, c1 = 0.f;
    float ylv = y[e & (B - 1)];                     // lanes 0..31 hold y block
    _Float16* h0h = (_Float16*)h0r;
    _Float16* h1h = (_Float16*)h1r;

    auto blk = [&](auto L0C, auto L1C, int k) {
      constexpr bool DL0 = decltype(L0C)::value;
      constexpr bool DL1 = decltype(L1C)::value;
      #pragma unroll 1
      for (int i = 0; i < B; ++i) {
        PINALLW(); PINALLX();
        if constexpr (DL0) {
          const int s = k * B + i;
          float ys = __builtin_bit_cast(float,
              __builtin_amdgcn_readlane(__builtin_bit_cast(int, ylv), i));
          const u4* hp = (const u4*)(h0r + ((s - 1) & (RS - 1)) * 32);
          u4 H0=hp[0],H1=hp[1],H2=hp[2],H3=hp[3],H4=hp[4],H5=hp[5],H6=hp[6],H7=hp[7];
          float ai0=0,ai1=0, af0=0,af1=0, ag0=0,ag1=0, ao0=0,ao1=0;
          DP4(ai0,W0,H0)  DP4(af0,W8,H0)  DP4(ag0,W16,H0) DP4(ao0,W24,H0)
          DP4(ai1,W1,H1)  DP4(af1,W9,H1)  DP4(ag1,W17,H1) DP4(ao1,W25,H1)
          DP4(ai0,W2,H2)  DP4(af0,W10,H2) DP4(ag0,W18,H2) DP4(ao0,W26,H2)
          DP4(ai1,W3,H3)  DP4(af1,W11,H3) DP4(ag1,W19,H3) DP4(ao1,W27,H3)
          DP4(ai0,W4,H4)  DP4(af0,W12,H4) DP4(ag0,W20,H4) DP4(ao0,W28,H4)
          DP4(ai1,W5,H5)  DP4(af1,W13,H5) DP4(ag1,W21,H5) DP4(ao1,W29,H5)
          DP4(ai0,W6,H6)  DP4(af0,W14,H6) DP4(ag0,W22,H6) DP4(ao0,W30,H6)
          DP4(ai1,W7,H7)  DP4(af1,W15,H7) DP4(ag1,W23,H7) DP4(ao1,W31,H7)
          float I = sig_n((ai0 + ai1) + fmaf(ys, wii, bbi));
          float F = sig_n((af0 + af1) + fmaf(ys, wif, bbf));
          float Gg = tanh_n((ag0 + ag1) + fmaf(ys, wig, bbg));
          float O = sig_n((ao0 + ao1) + fmaf(ys, wio, bbo));
          c0 = fmaf(F, c0, I * Gg);
          float h = O * tanh_cn(c0);
          h0h[(s & (RS - 1)) * 64 + e] = (_Float16)h;   // ds_write_b16
        }
        if constexpr (DL1) {
          const int t = k * B + i - 2 * B;
          const int slot = t & (RS - 1);
          const f4 xq = *(const f4*)(xpf + slot * 256 + e * 4);
          const u4* jp = (const u4*)(h1r + ((t - 1) & (RS - 1)) * 32);
          u4 J0=jp[0],J1=jp[1],J2=jp[2],J3=jp[3],J4=jp[4],J5=jp[5],J6=jp[6],J7=jp[7];
          float bi0=0,bi1=0, bf0=0,bf1=0, bg0=0,bg1=0, bo0=0,bo1=0;
          DP4(bi0,X0,J0)  DP4(bf0,X8,J0)  DP4(bg0,X16,J0) DP4(bo0,X24,J0)
          DP4(bi1,X1,J1)  DP4(bf1,X9,J1)  DP4(bg1,X17,J1) DP4(bo1,X25,J1)
          DP4(bi0,X2,J2)  DP4(bf0,X10,J2) DP4(bg0,X18,J2) DP4(bo0,X26,J2)
          DP4(bi1,X3,J3)  DP4(bf1,X11,J3) DP4(bg1,X19,J3) DP4(bo1,X27,J3)
          DP4(bi0,X4,J4)  DP4(bf0,X12,J4) DP4(bg0,X20,J4) DP4(bo0,X28,J4)
          DP4(bi1,X5,J5)  DP4(bf1,X13,J5) DP4(bg1,X21,J5) DP4(bo1,X29,J5)
          DP4(bi0,X6,J6)  DP4(bf0,X14,J6) DP4(bg0,X22,J6) DP4(bo0,X30,J6)
          DP4(bi1,X7,J7)  DP4(bf1,X15,J7) DP4(bg1,X23,J7) DP4(bo1,X31,J7)
          float I = sig_n(xq.x + (bi0 + bi1));
          float F = sig_n(xq.y + (bf0 + bf1));
          float Gg = tanh_n(xq.z + (bg0 + bg1));
          float O = sig_n(xq.w + (bo0 + bo1));
          c1 = fmaf(F, c1, I * Gg);
          float h = O * tanh_cn(c1);
          h1h[slot * 64 + e] = (_Float16)h;             // ds_write_b16
        }
      }
    };

    for (int k = 0; k < K_SS; ++k) {
      const bool l0 = (k < NB);
      const bool l1 = (k >= 2 && k <= NB + 1);
      float yln = (l0 && k + 1 < NB) ? y[(k + 1) * B + (e & (B - 1))] : 0.f;
      if (l0 && l1)      blk(TT{}, TT{}, k);
      else if (l0)       blk(TT{}, FF{}, k);
      else if (l1)       blk(FF{}, TT{}, k);
      ylv = yln;
      BARRIER();
    }
  } else {
    // ========= wave1: xp1 producer (block k-1) + head (block k-3) =========
    const int e = tid - 64;
    const u4* wp = (const u4*)(ws + 16384 + e * 128);   // Wih1 (negated-scaled)
    DECLW32(wp);
    const u4* hwp = (const u4*)(ws + 24576 + e * 8);
    u4 HW0 = hwp[0], HW1 = hwp[1];
    float bb0 = -(bih1[e] + bhh1[e]) * L2E;
    float bb1 = -(bih1[64 + e] + bhh1[64 + e]) * L2E;
    float bb2 = -(bih1[128 + e] + bhh1[128 + e]) * L2E2;
    float bb3 = -(bih1[192 + e] + bhh1[192 + e]) * L2E;
    const int m = e >> 2, kq = e & 3;
    float bl = (kq == 0) ? blin[m] : 0.f;

    for (int k = 0; k < K_SS; ++k) {
      if (k >= 1 && k <= NB) {                         // xp1 for block k-1
        const int base = (k - 1) * B;
        #pragma unroll 1
        for (int i = 0; i < B; ++i) {
          const int t = base + i;
          const int slot = t & (RS - 1);
          PINALLW();
          const u4* hp = (const u4*)(h0r + slot * 32);
          u4 H0=hp[0],H1=hp[1],H2=hp[2],H3=hp[3],H4=hp[4],H5=hp[5],H6=hp[6],H7=hp[7];
          float p0a=0,p0b=0, p1a=0,p1b=0, p2a=0,p2b=0, p3a=0,p3b=0;
          DP4(p0a,W0,H0) DP4(p1a,W8,H0)  DP4(p2a,W16,H0) DP4(p3a,W24,H0)
          DP4(p0b,W1,H1) DP4(p1b,W9,H1)  DP4(p2b,W17,H1) DP4(p3b,W25,H1)
          DP4(p0a,W2,H2) DP4(p1a,W10,H2) DP4(p2a,W18,H2) DP4(p3a,W26,H2)
          DP4(p0b,W3,H3) DP4(p1b,W11,H3) DP4(p2b,W19,H3) DP4(p3b,W27,H3)
          DP4(p0a,W4,H4) DP4(p1a,W12,H4) DP4(p2a,W20,H4) DP4(p3a,W28,H4)
          DP4(p0b,W5,H5) DP4(p1b,W13,H5) DP4(p2b,W21,H5) DP4(p3b,W29,H5)
          DP4(p0a,W6,H6) DP4(p1a,W14,H6) DP4(p2a,W22,H6) DP4(p3a,W30,H6)
          DP4(p0b,W7,H7) DP4(p1b,W15,H7) DP4(p2b,W23,H7) DP4(p3b,W31,H7)
          f4 v;
          v.x = (p0a + p0b) + bb0;
          v.y = (p1a + p1b) + bb1;
          v.z = (p2a + p2b) + bb2;
          v.w = (p3a + p3b) + bb3;
          *(f4*)(xpf + slot * 256 + e * 4) = v;        // one ds_write_b128
        }
      }
      if (k >= 3) {                                    // head for block k-3
        const int base = (k - 3) * B;
        #pragma unroll 1
        for (int i = 0; i < B; ++i) {
          const int t = base + i;
          const int slot = t & (RS - 1);
          const u4* h1p = (const u4*)(h1r + slot * 32 + kq * 8);
          u4 Y0 = h1p[0], Y1 = h1p[1];
          float r2 = 0.f;
          DP4(r2, HW0, Y0) DP4(r2, HW1, Y1)
          r2 += DPPX1(r2);
          r2 += DPPX2(r2);                             // sum over kq (quad)
          if (kq == 0) out[t * 16 + m] = r2 + bl;
        }
      }
      BARRIER();
    }
  }
}

extern "C" void kernel_launch(void* const* d_in, const int* in_sizes, int n_in,
                              void* d_out, int out_size, void* d_ws, size_t ws_size,
                              hipStream_t stream) {
  const float* y    = (const float*)d_in[0];
  const float* Wih0 = (const float*)d_in[1];
  const float* Whh0 = (const float*)d_in[2];
  const float* bih0 = (const float*)d_in[3];
  const float* bhh0 = (const float*)d_in[4];
  const float* Wih1 = (const float*)d_in[5];
  const float* Whh1 = (const float*)d_in[6];
  const float* bih1 = (const float*)d_in[7];
  const float* bhh1 = (const float*)d_in[8];
  const float* Wlin = (const float*)d_in[9];
  const float* blin = (const float*)d_in[10];
  unsigned* ws = (unsigned*)d_ws;                // 25088 dwords ~= 100 KB

  pack_w<<<dim3(98), dim3(256), 0, stream>>>(Whh0, Whh1, Wih1, Wlin, ws);
  rnn_fused<<<dim3(1), dim3(128), 0, stream>>>(
      y, Wih0, bih0, bhh0, bih1, bhh1, blin, ws, (float*)d_out);
}

// Round 5
// 114588.330 us; speedup vs baseline: 2.9640x; 2.9640x over previous
//
#include <hip/hip_runtime.h>

// RNNDetector: 2-layer LSTM (H=64), T=262144 sequential steps + 16-wide head.
// ROUND 15: R14 merged-wave spilled (VGPR 512, 3x regress) -> reverted to R13.
// R13's step model says ~620cyc @2.4GHz but we measure 1076 "cycles" -- the
// gap matches a PARKED SHADER CLOCK (~1.4-1.6GHz) on a 3-wave, 0.2%-busy,
// ~0-traffic kernel (DVFS governor sees an idle chip). THIS ROUND: controlled
// probe, single variable. Kernel = R13 bit-identical + 255 spinner WGs (one
// per remaining CU) doing light FMA+sleep loops, polling a done-flag set by
// the main WG at exit. If DVFS was parking SCLK, chip-wide activity boosts it
// and the serial chain speeds up for free; if not, dur is unchanged and the
// clock hypothesis is dead (next: MFMA-based step under the rate hypothesis).

constexpr int T  = 262144;
constexpr int B  = 32;          // steps per superstep
constexpr int NB = T / B;       // 8192 blocks
constexpr int RS = 2 * B;       // 64 ring slots (2 blocks)
constexpr int K_SS = NB + 3;    // supersteps incl. pipeline drain
constexpr int FLAG = 25088;     // ws dword: done-flag for spinner WGs

typedef _Float16 h2v __attribute__((ext_vector_type(2)));
typedef unsigned u4 __attribute__((ext_vector_type(4)));
typedef float    f4 __attribute__((ext_vector_type(4)));

__device__ __forceinline__ float rcp_f(float x) { return __builtin_amdgcn_rcpf(x); }

#define BARRIER() asm volatile("s_waitcnt lgkmcnt(0)\n\ts_barrier" ::: "memory")

// packed-f16 dot2: acc += w.lo*h.lo + w.hi*h.hi (f32 accumulate)
static __device__ __forceinline__ float fd(unsigned w, unsigned h, float acc) {
#if __has_builtin(__builtin_amdgcn_fdot2)
  return __builtin_amdgcn_fdot2(__builtin_bit_cast(h2v, w),
                                __builtin_bit_cast(h2v, h), acc, false);
#else
  h2v a = __builtin_bit_cast(h2v, w), b = __builtin_bit_cast(h2v, h);
  acc = fmaf((float)a.x, (float)b.x, acc);
  acc = fmaf((float)a.y, (float)b.y, acc);
  return acc;
#endif
}

#define DP4(acc, W, H) { acc = fd((W).x, (H).x, acc); acc = fd((W).y, (H).y, acc); \
                         acc = fd((W).z, (H).z, acc); acc = fd((W).w, (H).w, acc); }

// quad_perm DPP cross-lane (pure VALU, no LDS): xor1 = 0xB1, xor2 = 0x4E
#define DPPX1(x) __builtin_bit_cast(float, __builtin_amdgcn_mov_dpp(            \
                    __builtin_bit_cast(int, (x)), 0xB1, 0xF, 0xF, true))
#define DPPX2(x) __builtin_bit_cast(float, __builtin_amdgcn_mov_dpp(            \
                    __builtin_bit_cast(int, (x)), 0x4E, 0xF, 0xF, true))

// raw v_exp_f32 (2^x). gfx9-lineage: VALU->VALU interlocked, safe as asm.
__device__ __forceinline__ float exp2_f(float x) {
  float r; asm("v_exp_f32 %0, %1" : "=v"(r) : "v"(x)); return r;
}
// exp2(-u), guarded against +overflow (u <= -126 -> cap; u >> 0 underflows to 0)
__device__ __forceinline__ float exp2n_g(float u) {
  return exp2_f(fminf(-u, 126.f));
}
// u = log2e * x  ->  sigmoid(x)
__device__ __forceinline__ float sig_u(float u) {
  return rcp_f(1.f + exp2n_g(u));
}
// u = 2*log2e * z  ->  tanh(z)
__device__ __forceinline__ float tanh_u(float u) {
  float e2 = exp2n_g(u);
  return (1.f - e2) * rcp_f(1.f + e2);
}
// real-unit tanh (for cell state)
__device__ __forceinline__ float tanh_c(float c) {
  return tanh_u(c * 2.8853900817779268f);
}

constexpr float L2E  = 1.4426950408889634f;
constexpr float L2E2 = 2.8853900817779268f;

// f32 -> f16 RNE (|w| < ~2 after prescale: no overflow; flush sub-6e-5 to 0)
__device__ unsigned f16rne(float f) {
  unsigned u = __float_as_uint(f);
  unsigned s = (u >> 16) & 0x8000u;
  int e = (int)((u >> 23) & 0xff) - 127;
  unsigned m = u & 0x7fffffu;
  if (e < -14) return s;
  unsigned h = s | (unsigned)((e + 15) << 10) | (m >> 13);
  unsigned rem = m & 0x1fffu;
  h += (rem > 0x1000u) || (rem == 0x1000u && (h & 1u));
  return h;
}

// ---- prepass: pack f16 weights, per-(wave,lane)-contiguous, exp2-prescaled --
// All three 256x64 matrices share one layout: lane l, dword d (0..127):
//   r = d>>5 (gate i/f/g/o), kp = d&31, row = r*64+l, cols (2kp, 2kp+1).
//   scale = 2*log2e for gate g (r==2), log2e otherwise.
// region A [    0, 8192): Whh0  (wave0)
// region B [ 8192,16384): Whh1  (wave2)
// region C [16384,24576): Wih1  (wave1)
// region E [24576,25088): head: lane l (m=l>>2,kq=l&3), d=0..7:
//   Wlin[m][kq*16+2d], +1  (unscaled)
__global__ void pack_w(const float* __restrict__ Whh0,
                       const float* __restrict__ Whh1,
                       const float* __restrict__ Wih1,
                       const float* __restrict__ Wlin,
                       unsigned* __restrict__ ws) {
  if (blockIdx.x == 0 && threadIdx.x == 0) ws[FLAG] = 0u;
  int i = blockIdx.x * 256 + threadIdx.x;
  if (i >= 25088) return;
  float v0, v1, sc = 1.f;
  if (i < 24576) {
    int w = i >> 13, rem = i & 8191, l = rem >> 7, d = rem & 127;
    int r = d >> 5, kp = d & 31, row = r * 64 + l;
    const float* src = (w == 0) ? Whh0 : (w == 1) ? Whh1 : Wih1;
    v0 = src[row * 64 + 2 * kp]; v1 = src[row * 64 + 2 * kp + 1];
    sc = (r == 2) ? L2E2 : L2E;
  } else {
    int j = i - 24576, l = j >> 3, d = j & 7;
    int m = l >> 2, kq = l & 3, k = kq * 16 + 2 * d;
    v0 = Wlin[m * 64 + k]; v1 = Wlin[m * 64 + k + 1];
  }
  ws[i] = f16rne(v0 * sc) | (f16rne(v1 * sc) << 16);
}

#define DECLW32(wp)                                                            \
  u4 W0=(wp)[0],  W1=(wp)[1],  W2=(wp)[2],  W3=(wp)[3],                        \
     W4=(wp)[4],  W5=(wp)[5],  W6=(wp)[6],  W7=(wp)[7],                        \
     W8=(wp)[8],  W9=(wp)[9],  W10=(wp)[10],W11=(wp)[11],                      \
     W12=(wp)[12],W13=(wp)[13],W14=(wp)[14],W15=(wp)[15],                      \
     W16=(wp)[16],W17=(wp)[17],W18=(wp)[18],W19=(wp)[19],                      \
     W20=(wp)[20],W21=(wp)[21],W22=(wp)[22],W23=(wp)[23],                      \
     W24=(wp)[24],W25=(wp)[25],W26=(wp)[26],W27=(wp)[27],                      \
     W28=(wp)[28],W29=(wp)[29],W30=(wp)[30],W31=(wp)[31]

#define PINW8(a,b,c,d,e,f,g,h)                                                 \
  asm volatile("" : "+v"(a), "+v"(b), "+v"(c), "+v"(d),                        \
                    "+v"(e), "+v"(f), "+v"(g), "+v"(h))
#define PINALL() { PINW8(W0,W1,W2,W3,W4,W5,W6,W7);                             \
                   PINW8(W8,W9,W10,W11,W12,W13,W14,W15);                       \
                   PINW8(W16,W17,W18,W19,W20,W21,W22,W23);                     \
                   PINW8(W24,W25,W26,W27,W28,W29,W30,W31); }

__global__ __launch_bounds__(192)
__attribute__((amdgpu_waves_per_eu(1, 1)))
void rnn_fused(
    const float* __restrict__ y,
    const float* __restrict__ Wih0, const float* __restrict__ bih0,
    const float* __restrict__ bhh0,
    const float* __restrict__ bih1, const float* __restrict__ bhh1,
    const float* __restrict__ blin,
    unsigned* __restrict__ ws,
    float* __restrict__ out)
{
  const int tid = threadIdx.x;

  if (blockIdx.x != 0) {
    // ============ spinner WGs: keep the DVFS governor awake ============
    const int* flag = (const int*)(ws + FLAG);
    float a = 1.0001f;
    const float bq = 0.9999f, cq = 1e-4f;
    while (__hip_atomic_load(flag, __ATOMIC_RELAXED, __HIP_MEMORY_SCOPE_AGENT) == 0) {
      #pragma unroll
      for (int q = 0; q < 64; ++q) a = fmaf(a, bq, cq);
      __builtin_amdgcn_s_sleep(1);
    }
    asm volatile("" :: "v"(a));
    return;
  }

  // rings: block j occupies slots [j*B .. j*B+B) & (RS-1) — adjacent blocks
  // land in disjoint halves, so all cross-wave same-slot reuse is >= 1
  // barrier apart.
  __shared__ __align__(16) unsigned h0r[RS * 32];   // h0 f16, 8 KB
  __shared__ __align__(16) unsigned h1r[RS * 32];   // h1 f16, 8 KB
  __shared__ __align__(16) float    xpf[RS * 256];  // xp1 f32 elem-major, 64 KB

  for (int j = tid; j < RS * 32; j += 192) { h0r[j] = 0u; h1r[j] = 0u; }
  __syncthreads();

  if (tid < 64) {
    // ================= wave0: layer 0, all 4 gates per lane =================
    __builtin_amdgcn_s_setprio(1);
    const int e = tid;
    const u4* wp = (const u4*)(ws + e * 128);
    DECLW32(wp);
    float bbi = (bih0[e] + bhh0[e]) * L2E;
    float bbf = (bih0[64 + e] + bhh0[64 + e]) * L2E;
    float bbg = (bih0[128 + e] + bhh0[128 + e]) * L2E2;
    float bbo = (bih0[192 + e] + bhh0[192 + e]) * L2E;
    float wii = Wih0[e] * L2E, wif = Wih0[64 + e] * L2E;
    float wig = Wih0[128 + e] * L2E2, wio = Wih0[192 + e] * L2E;
    float c0 = 0.f;
    float ylv = y[e & (B - 1)];                       // lanes 0..31 hold y[0..31]
    _Float16* h0h = (_Float16*)h0r;

    for (int k = 0; k < K_SS; ++k) {
      if (k < NB) {
        float yln = (k + 1 < NB) ? y[(k + 1) * B + (e & (B - 1))] : 0.f;
        const int base = k * B;
        #pragma unroll 1
        for (int i = 0; i < B; ++i) {
          const int s = base + i;
          PINALL();
          float ys = __builtin_bit_cast(float,
              __builtin_amdgcn_readlane(__builtin_bit_cast(int, ylv), i));
          const u4* hp = (const u4*)(h0r + ((s - 1) & (RS - 1)) * 32);
          u4 H0=hp[0],H1=hp[1],H2=hp[2],H3=hp[3],H4=hp[4],H5=hp[5],H6=hp[6],H7=hp[7];
          float ai0=0,ai1=0, af0=0,af1=0, ag0=0,ag1=0, ao0=0,ao1=0;
          DP4(ai0,W0,H0)  DP4(af0,W8,H0)  DP4(ag0,W16,H0) DP4(ao0,W24,H0)
          DP4(ai1,W1,H1)  DP4(af1,W9,H1)  DP4(ag1,W17,H1) DP4(ao1,W25,H1)
          DP4(ai0,W2,H2)  DP4(af0,W10,H2) DP4(ag0,W18,H2) DP4(ao0,W26,H2)
          DP4(ai1,W3,H3)  DP4(af1,W11,H3) DP4(ag1,W19,H3) DP4(ao1,W27,H3)
          DP4(ai0,W4,H4)  DP4(af0,W12,H4) DP4(ag0,W20,H4) DP4(ao0,W28,H4)
          DP4(ai1,W5,H5)  DP4(af1,W13,H5) DP4(ag1,W21,H5) DP4(ao1,W29,H5)
          DP4(ai0,W6,H6)  DP4(af0,W14,H6) DP4(ag0,W22,H6) DP4(ao0,W30,H6)
          DP4(ai1,W7,H7)  DP4(af1,W15,H7) DP4(ag1,W23,H7) DP4(ao1,W31,H7)
          float I = sig_u((ai0 + ai1) + fmaf(ys, wii, bbi));
          float F = sig_u((af0 + af1) + fmaf(ys, wif, bbf));
          float G = tanh_u((ag0 + ag1) + fmaf(ys, wig, bbg));
          float O = sig_u((ao0 + ao1) + fmaf(ys, wio, bbo));
          c0 = fmaf(F, c0, I * G);
          float h = O * tanh_c(c0);
          h0h[(s & (RS - 1)) * 64 + e] = (_Float16)h;   // ds_write_b16
        }
        ylv = yln;
      }
      BARRIER();
    }
  } else if (tid < 128) {
    // ========= wave1: xp1 producer (block k-1) + head (block k-3) =========
    const int e = tid - 64;
    const u4* wp = (const u4*)(ws + 16384 + e * 128);
    DECLW32(wp);
    const u4* hwp = (const u4*)(ws + 24576 + e * 8);
    u4 HW0 = hwp[0], HW1 = hwp[1];
    float bb0 = (bih1[e] + bhh1[e]) * L2E;
    float bb1 = (bih1[64 + e] + bhh1[64 + e]) * L2E;
    float bb2 = (bih1[128 + e] + bhh1[128 + e]) * L2E2;
    float bb3 = (bih1[192 + e] + bhh1[192 + e]) * L2E;
    const int m = e >> 2, kq = e & 3;
    float bl = (kq == 0) ? blin[m] : 0.f;

    for (int k = 0; k < K_SS; ++k) {
      if (k >= 1 && k <= NB) {                         // xp1 for block k-1
        const int base = (k - 1) * B;
        #pragma unroll 1
        for (int i = 0; i < B; ++i) {
          const int t = base + i;
          const int slot = t & (RS - 1);
          PINALL();
          const u4* hp = (const u4*)(h0r + slot * 32);
          u4 H0=hp[0],H1=hp[1],H2=hp[2],H3=hp[3],H4=hp[4],H5=hp[5],H6=hp[6],H7=hp[7];
          float p0a=0,p0b=0, p1a=0,p1b=0, p2a=0,p2b=0, p3a=0,p3b=0;
          DP4(p0a,W0,H0) DP4(p1a,W8,H0)  DP4(p2a,W16,H0) DP4(p3a,W24,H0)
          DP4(p0b,W1,H1) DP4(p1b,W9,H1)  DP4(p2b,W17,H1) DP4(p3b,W25,H1)
          DP4(p0a,W2,H2) DP4(p1a,W10,H2) DP4(p2a,W18,H2) DP4(p3a,W26,H2)
          DP4(p0b,W3,H3) DP4(p1b,W11,H3) DP4(p2b,W19,H3) DP4(p3b,W27,H3)
          DP4(p0a,W4,H4) DP4(p1a,W12,H4) DP4(p2a,W20,H4) DP4(p3a,W28,H4)
          DP4(p0b,W5,H5) DP4(p1b,W13,H5) DP4(p2b,W21,H5) DP4(p3b,W29,H5)
          DP4(p0a,W6,H6) DP4(p1a,W14,H6) DP4(p2a,W22,H6) DP4(p3a,W30,H6)
          DP4(p0b,W7,H7) DP4(p1b,W15,H7) DP4(p2b,W23,H7) DP4(p3b,W31,H7)
          f4 v;
          v.x = (p0a + p0b) + bb0;
          v.y = (p1a + p1b) + bb1;
          v.z = (p2a + p2b) + bb2;
          v.w = (p3a + p3b) + bb3;
          *(f4*)(xpf + slot * 256 + e * 4) = v;        // one ds_write_b128
        }
      }
      if (k >= 3) {                                    // head for block k-3
        const int base = (k - 3) * B;
        #pragma unroll 1
        for (int i = 0; i < B; ++i) {
          const int t = base + i;
          const int slot = t & (RS - 1);
          const u4* h1p = (const u4*)(h1r + slot * 32 + kq * 8);
          u4 X0 = h1p[0], X1 = h1p[1];
          float r2 = 0.f;
          DP4(r2, HW0, X0) DP4(r2, HW1, X1)
          r2 += DPPX1(r2);
          r2 += DPPX2(r2);                             // sum over kq (quad)
          if (kq == 0) out[t * 16 + m] = r2 + bl;
        }
      }
      BARRIER();
    }
  } else {
    // ============ wave2: layer-1 recurrence (block k-2), in-lane ============
    __builtin_amdgcn_s_setprio(1);
    const int e = tid - 128;
    const u4* wp = (const u4*)(ws + 8192 + e * 128);
    DECLW32(wp);
    float c1 = 0.f;
    _Float16* h1h = (_Float16*)h1r;

    for (int k = 0; k < K_SS; ++k) {
      if (k >= 2 && k <= NB + 1) {
        const int base = (k - 2) * B;
        #pragma unroll 1
        for (int i = 0; i < B; ++i) {
          const int t = base + i;
          const int slot = t & (RS - 1);
          PINALL();
          const f4 xq = *(const f4*)(xpf + slot * 256 + e * 4);  // hoisted b128
          const u4* hp = (const u4*)(h1r + ((t - 1) & (RS - 1)) * 32);
          u4 H0=hp[0],H1=hp[1],H2=hp[2],H3=hp[3],H4=hp[4],H5=hp[5],H6=hp[6],H7=hp[7];
          float ai0=0,ai1=0, af0=0,af1=0, ag0=0,ag1=0, ao0=0,ao1=0;
          DP4(ai0,W0,H0)  DP4(af0,W8,H0)  DP4(ag0,W16,H0) DP4(ao0,W24,H0)
          DP4(ai1,W1,H1)  DP4(af1,W9,H1)  DP4(ag1,W17,H1) DP4(ao1,W25,H1)
          DP4(ai0,W2,H2)  DP4(af0,W10,H2) DP4(ag0,W18,H2) DP4(ao0,W26,H2)
          DP4(ai1,W3,H3)  DP4(af1,W11,H3) DP4(ag1,W19,H3) DP4(ao1,W27,H3)
          DP4(ai0,W4,H4)  DP4(af0,W12,H4) DP4(ag0,W20,H4) DP4(ao0,W28,H4)
          DP4(ai1,W5,H5)  DP4(af1,W13,H5) DP4(ag1,W21,H5) DP4(ao1,W29,H5)
          DP4(ai0,W6,H6)  DP4(af0,W14,H6) DP4(ag0,W22,H6) DP4(ao0,W30,H6)
          DP4(ai1,W7,H7)  DP4(af1,W15,H7) DP4(ag1,W23,H7) DP4(ao1,W31,H7)
          float I = sig_u(xq.x + (ai0 + ai1));
          float F = sig_u(xq.y + (af0 + af1));
          float G = tanh_u(xq.z + (ag0 + ag1));
          float O = sig_u(xq.w + (ao0 + ao1));
          c1 = fmaf(F, c1, I * G);
          float h = O * tanh_c(c1);
          h1h[slot * 64 + e] = (_Float16)h;            // ds_write_b16
        }
      }
      BARRIER();
    }
  }

  // all three waves done: release the spinner WGs
  __syncthreads();
  if (tid == 0)
    __hip_atomic_store((int*)(ws + FLAG), 1, __ATOMIC_RELEASE,
                       __HIP_MEMORY_SCOPE_AGENT);
}

extern "C" void kernel_launch(void* const* d_in, const int* in_sizes, int n_in,
                              void* d_out, int out_size, void* d_ws, size_t ws_size,
                              hipStream_t stream) {
  const float* y    = (const float*)d_in[0];
  const float* Wih0 = (const float*)d_in[1];
  const float* Whh0 = (const float*)d_in[2];
  const float* bih0 = (const float*)d_in[3];
  const float* bhh0 = (const float*)d_in[4];
  const float* Wih1 = (const float*)d_in[5];
  const float* Whh1 = (const float*)d_in[6];
  const float* bih1 = (const float*)d_in[7];
  const float* bhh1 = (const float*)d_in[8];
  const float* Wlin = (const float*)d_in[9];
  const float* blin = (const float*)d_in[10];
  unsigned* ws = (unsigned*)d_ws;                // 25089 dwords ~= 100 KB

  pack_w<<<dim3(98), dim3(256), 0, stream>>>(Whh0, Whh1, Wih1, Wlin, ws);
  rnn_fused<<<dim3(256), dim3(192), 0, stream>>>(
      y, Wih0, bih0, bhh0, bih1, bhh1, blin, ws, (float*)d_out);
}

// Round 6
// 109702.856 us; speedup vs baseline: 3.0960x; 1.0445x over previous
//
#include <hip/hip_runtime.h>

// RNNDetector: 2-layer LSTM (H=64), T=262144 sequential steps + 16-wide head.
// ROUND 16: R15 spinner probe KILLED the DVFS theory (dur unchanged with 255
// spinner WGs). Re-reading VALUBusy per-SIMD: 0.205% x 1024 SIMDs / 3 waves
// ~= 70% VALU-busy per recurrence wave -> ISSUE-bound, and the issue census
// only closes if v_dot2_f32_f16 is a HALF-RATE op (~4cyc/wave64; fp32 peak
// arithmetic says plain v_fma_f32 owns the 2cyc slot). THIS ROUND: recurrence
// dot engines switch fdot2 -> v_pk_fma_f16 (full-rate packed-f16 pipe,
// 2 MACs/lane/instr at 2cyc): same 128 instrs/step, half the issue cycles.
// f16 accumulators (8 chains x 16 deep); per-gate combine = v_pk_add_f16 +
// one fdot2 vs (1,1) which converts+sums into f32 with bias folded in.
// Wave1 (xp/head, not critical-path) stays on fdot2. Spinners removed.
// Error budget: f16 accum adds ~1e-3 gate noise -> ~2.5e-4 on h, an order
// below the existing 2e-3 f16-h quantization.

constexpr int T  = 262144;
constexpr int B  = 32;          // steps per superstep
constexpr int NB = T / B;       // 8192 blocks
constexpr int RS = 2 * B;       // 64 ring slots (2 blocks)
constexpr int K_SS = NB + 3;    // supersteps incl. pipeline drain

typedef _Float16 h2v __attribute__((ext_vector_type(2)));
typedef unsigned u4 __attribute__((ext_vector_type(4)));
typedef float    f4 __attribute__((ext_vector_type(4)));

__device__ __forceinline__ float rcp_f(float x) { return __builtin_amdgcn_rcpf(x); }

#define BARRIER() asm volatile("s_waitcnt lgkmcnt(0)\n\ts_barrier" ::: "memory")

// packed-f16 dot2: acc += w.lo*h.lo + w.hi*h.hi (f32 accumulate)
static __device__ __forceinline__ float fd(unsigned w, unsigned h, float acc) {
#if __has_builtin(__builtin_amdgcn_fdot2)
  return __builtin_amdgcn_fdot2(__builtin_bit_cast(h2v, w),
                                __builtin_bit_cast(h2v, h), acc, false);
#else
  h2v a = __builtin_bit_cast(h2v, w), b = __builtin_bit_cast(h2v, h);
  acc = fmaf((float)a.x, (float)b.x, acc);
  acc = fmaf((float)a.y, (float)b.y, acc);
  return acc;
#endif
}

#define DP4(acc, W, H) { acc = fd((W).x, (H).x, acc); acc = fd((W).y, (H).y, acc); \
                         acc = fd((W).z, (H).z, acc); acc = fd((W).w, (H).w, acc); }

// packed-f16 FMA: acc(h2v) += w * h   (v_pk_fma_f16, full-rate pipe)
__device__ __forceinline__ h2v b2h(unsigned u) { return __builtin_bit_cast(h2v, u); }
#if __has_builtin(__builtin_elementwise_fma)
#define DPH(acc, Wd, Hd) acc = __builtin_elementwise_fma(b2h(Wd), b2h(Hd), acc);
#else
#define DPH(acc, Wd, Hd) acc = b2h(Wd) * b2h(Hd) + acc;
#endif
#define DP4H(acc, W, H) { DPH(acc, (W).x, (H).x) DPH(acc, (W).y, (H).y) \
                          DPH(acc, (W).z, (H).z) DPH(acc, (W).w, (H).w) }
constexpr unsigned ONES2 = 0x3C003C00u;   // (f16)1.0 pair

// quad_perm DPP cross-lane (pure VALU, no LDS): xor1 = 0xB1, xor2 = 0x4E
#define DPPX1(x) __builtin_bit_cast(float, __builtin_amdgcn_mov_dpp(            \
                    __builtin_bit_cast(int, (x)), 0xB1, 0xF, 0xF, true))
#define DPPX2(x) __builtin_bit_cast(float, __builtin_amdgcn_mov_dpp(            \
                    __builtin_bit_cast(int, (x)), 0x4E, 0xF, 0xF, true))

// raw v_exp_f32 (2^x). gfx9-lineage: VALU->VALU interlocked, safe as asm.
__device__ __forceinline__ float exp2_f(float x) {
  float r; asm("v_exp_f32 %0, %1" : "=v"(r) : "v"(x)); return r;
}
// exp2(-u), guarded against +overflow (u <= -126 -> cap; u >> 0 underflows to 0)
__device__ __forceinline__ float exp2n_g(float u) {
  return exp2_f(fminf(-u, 126.f));
}
// u = log2e * x  ->  sigmoid(x)
__device__ __forceinline__ float sig_u(float u) {
  return rcp_f(1.f + exp2n_g(u));
}
// u = 2*log2e * z  ->  tanh(z)
__device__ __forceinline__ float tanh_u(float u) {
  float e2 = exp2n_g(u);
  return (1.f - e2) * rcp_f(1.f + e2);
}
// real-unit tanh (for cell state)
__device__ __forceinline__ float tanh_c(float c) {
  return tanh_u(c * 2.8853900817779268f);
}

constexpr float L2E  = 1.4426950408889634f;
constexpr float L2E2 = 2.8853900817779268f;

// f32 -> f16 RNE (|w| < ~2 after prescale: no overflow; flush sub-6e-5 to 0)
__device__ unsigned f16rne(float f) {
  unsigned u = __float_as_uint(f);
  unsigned s = (u >> 16) & 0x8000u;
  int e = (int)((u >> 23) & 0xff) - 127;
  unsigned m = u & 0x7fffffu;
  if (e < -14) return s;
  unsigned h = s | (unsigned)((e + 15) << 10) | (m >> 13);
  unsigned rem = m & 0x1fffu;
  h += (rem > 0x1000u) || (rem == 0x1000u && (h & 1u));
  return h;
}

// ---- prepass: pack f16 weights, per-(wave,lane)-contiguous, exp2-prescaled --
// All three 256x64 matrices share one layout: lane l, dword d (0..127):
//   r = d>>5 (gate i/f/g/o), kp = d&31, row = r*64+l, cols (2kp, 2kp+1).
//   scale = 2*log2e for gate g (r==2), log2e otherwise.
// region A [    0, 8192): Whh0  (wave0)
// region B [ 8192,16384): Whh1  (wave2)
// region C [16384,24576): Wih1  (wave1)
// region E [24576,25088): head: lane l (m=l>>2,kq=l&3), d=0..7:
//   Wlin[m][kq*16+2d], +1  (unscaled)
__global__ void pack_w(const float* __restrict__ Whh0,
                       const float* __restrict__ Whh1,
                       const float* __restrict__ Wih1,
                       const float* __restrict__ Wlin,
                       unsigned* __restrict__ ws) {
  int i = blockIdx.x * 256 + threadIdx.x;
  if (i >= 25088) return;
  float v0, v1, sc = 1.f;
  if (i < 24576) {
    int w = i >> 13, rem = i & 8191, l = rem >> 7, d = rem & 127;
    int r = d >> 5, kp = d & 31, row = r * 64 + l;
    const float* src = (w == 0) ? Whh0 : (w == 1) ? Whh1 : Wih1;
    v0 = src[row * 64 + 2 * kp]; v1 = src[row * 64 + 2 * kp + 1];
    sc = (r == 2) ? L2E2 : L2E;
  } else {
    int j = i - 24576, l = j >> 3, d = j & 7;
    int m = l >> 2, kq = l & 3, k = kq * 16 + 2 * d;
    v0 = Wlin[m * 64 + k]; v1 = Wlin[m * 64 + k + 1];
  }
  ws[i] = f16rne(v0 * sc) | (f16rne(v1 * sc) << 16);
}

#define DECLW32(wp)                                                            \
  u4 W0=(wp)[0],  W1=(wp)[1],  W2=(wp)[2],  W3=(wp)[3],                        \
     W4=(wp)[4],  W5=(wp)[5],  W6=(wp)[6],  W7=(wp)[7],                        \
     W8=(wp)[8],  W9=(wp)[9],  W10=(wp)[10],W11=(wp)[11],                      \
     W12=(wp)[12],W13=(wp)[13],W14=(wp)[14],W15=(wp)[15],                      \
     W16=(wp)[16],W17=(wp)[17],W18=(wp)[18],W19=(wp)[19],                      \
     W20=(wp)[20],W21=(wp)[21],W22=(wp)[22],W23=(wp)[23],                      \
     W24=(wp)[24],W25=(wp)[25],W26=(wp)[26],W27=(wp)[27],                      \
     W28=(wp)[28],W29=(wp)[29],W30=(wp)[30],W31=(wp)[31]

#define PINW8(a,b,c,d,e,f,g,h)                                                 \
  asm volatile("" : "+v"(a), "+v"(b), "+v"(c), "+v"(d),                        \
                    "+v"(e), "+v"(f), "+v"(g), "+v"(h))
#define PINALL() { PINW8(W0,W1,W2,W3,W4,W5,W6,W7);                             \
                   PINW8(W8,W9,W10,W11,W12,W13,W14,W15);                       \
                   PINW8(W16,W17,W18,W19,W20,W21,W22,W23);                     \
                   PINW8(W24,W25,W26,W27,W28,W29,W30,W31); }

__global__ __launch_bounds__(192)
__attribute__((amdgpu_waves_per_eu(1, 1)))
void rnn_fused(
    const float* __restrict__ y,
    const float* __restrict__ Wih0, const float* __restrict__ bih0,
    const float* __restrict__ bhh0,
    const float* __restrict__ bih1, const float* __restrict__ bhh1,
    const float* __restrict__ blin,
    const unsigned* __restrict__ ws,
    float* __restrict__ out)
{
  const int tid = threadIdx.x;
  // rings: block j occupies slots [j*B .. j*B+B) & (RS-1) — adjacent blocks
  // land in disjoint halves, so all cross-wave same-slot reuse is >= 1
  // barrier apart.
  __shared__ __align__(16) unsigned h0r[RS * 32];   // h0 f16, 8 KB
  __shared__ __align__(16) unsigned h1r[RS * 32];   // h1 f16, 8 KB
  __shared__ __align__(16) float    xpf[RS * 256];  // xp1 f32 elem-major, 64 KB

  for (int j = tid; j < RS * 32; j += 192) { h0r[j] = 0u; h1r[j] = 0u; }
  __syncthreads();

  if (tid < 64) {
    // ================= wave0: layer 0, all 4 gates per lane =================
    __builtin_amdgcn_s_setprio(1);
    const int e = tid;
    const u4* wp = (const u4*)(ws + e * 128);
    DECLW32(wp);
    float bbi = (bih0[e] + bhh0[e]) * L2E;
    float bbf = (bih0[64 + e] + bhh0[64 + e]) * L2E;
    float bbg = (bih0[128 + e] + bhh0[128 + e]) * L2E2;
    float bbo = (bih0[192 + e] + bhh0[192 + e]) * L2E;
    float wii = Wih0[e] * L2E, wif = Wih0[64 + e] * L2E;
    float wig = Wih0[128 + e] * L2E2, wio = Wih0[192 + e] * L2E;
    float c0 = 0.f;
    float ylv = y[e & (B - 1)];                       // lanes 0..31 hold y[0..31]
    _Float16* h0h = (_Float16*)h0r;

    for (int k = 0; k < K_SS; ++k) {
      if (k < NB) {
        float yln = (k + 1 < NB) ? y[(k + 1) * B + (e & (B - 1))] : 0.f;
        const int base = k * B;
        #pragma unroll 1
        for (int i = 0; i < B; ++i) {
          const int s = base + i;
          PINALL();
          float ys = __builtin_bit_cast(float,
              __builtin_amdgcn_readlane(__builtin_bit_cast(int, ylv), i));
          const u4* hp = (const u4*)(h0r + ((s - 1) & (RS - 1)) * 32);
          u4 H0=hp[0],H1=hp[1],H2=hp[2],H3=hp[3],H4=hp[4],H5=hp[5],H6=hp[6],H7=hp[7];
          h2v ai0={0,0},ai1={0,0}, af0={0,0},af1={0,0},
              ag0={0,0},ag1={0,0}, ao0={0,0},ao1={0,0};
          DP4H(ai0,W0,H0)  DP4H(af0,W8,H0)  DP4H(ag0,W16,H0) DP4H(ao0,W24,H0)
          DP4H(ai1,W1,H1)  DP4H(af1,W9,H1)  DP4H(ag1,W17,H1) DP4H(ao1,W25,H1)
          DP4H(ai0,W2,H2)  DP4H(af0,W10,H2) DP4H(ag0,W18,H2) DP4H(ao0,W26,H2)
          DP4H(ai1,W3,H3)  DP4H(af1,W11,H3) DP4H(ag1,W19,H3) DP4H(ao1,W27,H3)
          DP4H(ai0,W4,H4)  DP4H(af0,W12,H4) DP4H(ag0,W20,H4) DP4H(ao0,W28,H4)
          DP4H(ai1,W5,H5)  DP4H(af1,W13,H5) DP4H(ag1,W21,H5) DP4H(ao1,W29,H5)
          DP4H(ai0,W6,H6)  DP4H(af0,W14,H6) DP4H(ag0,W22,H6) DP4H(ao0,W30,H6)
          DP4H(ai1,W7,H7)  DP4H(af1,W15,H7) DP4H(ag1,W23,H7) DP4H(ao1,W31,H7)
          float I = sig_u(fd(__builtin_bit_cast(unsigned, ai0 + ai1), ONES2,
                             fmaf(ys, wii, bbi)));
          float F = sig_u(fd(__builtin_bit_cast(unsigned, af0 + af1), ONES2,
                             fmaf(ys, wif, bbf)));
          float G = tanh_u(fd(__builtin_bit_cast(unsigned, ag0 + ag1), ONES2,
                              fmaf(ys, wig, bbg)));
          float O = sig_u(fd(__builtin_bit_cast(unsigned, ao0 + ao1), ONES2,
                             fmaf(ys, wio, bbo)));
          c0 = fmaf(F, c0, I * G);
          float h = O * tanh_c(c0);
          h0h[(s & (RS - 1)) * 64 + e] = (_Float16)h;   // ds_write_b16
        }
        ylv = yln;
      }
      BARRIER();
    }
  } else if (tid < 128) {
    // ========= wave1: xp1 producer (block k-1) + head (block k-3) =========
    const int e = tid - 64;
    const u4* wp = (const u4*)(ws + 16384 + e * 128);
    DECLW32(wp);
    const u4* hwp = (const u4*)(ws + 24576 + e * 8);
    u4 HW0 = hwp[0], HW1 = hwp[1];
    float bb0 = (bih1[e] + bhh1[e]) * L2E;
    float bb1 = (bih1[64 + e] + bhh1[64 + e]) * L2E;
    float bb2 = (bih1[128 + e] + bhh1[128 + e]) * L2E2;
    float bb3 = (bih1[192 + e] + bhh1[192 + e]) * L2E;
    const int m = e >> 2, kq = e & 3;
    float bl = (kq == 0) ? blin[m] : 0.f;

    for (int k = 0; k < K_SS; ++k) {
      if (k >= 1 && k <= NB) {                         // xp1 for block k-1
        const int base = (k - 1) * B;
        #pragma unroll 1
        for (int i = 0; i < B; ++i) {
          const int t = base + i;
          const int slot = t & (RS - 1);
          PINALL();
          const u4* hp = (const u4*)(h0r + slot * 32);
          u4 H0=hp[0],H1=hp[1],H2=hp[2],H3=hp[3],H4=hp[4],H5=hp[5],H6=hp[6],H7=hp[7];
          float p0a=0,p0b=0, p1a=0,p1b=0, p2a=0,p2b=0, p3a=0,p3b=0;
          DP4(p0a,W0,H0) DP4(p1a,W8,H0)  DP4(p2a,W16,H0) DP4(p3a,W24,H0)
          DP4(p0b,W1,H1) DP4(p1b,W9,H1)  DP4(p2b,W17,H1) DP4(p3b,W25,H1)
          DP4(p0a,W2,H2) DP4(p1a,W10,H2) DP4(p2a,W18,H2) DP4(p3a,W26,H2)
          DP4(p0b,W3,H3) DP4(p1b,W11,H3) DP4(p2b,W19,H3) DP4(p3b,W27,H3)
          DP4(p0a,W4,H4) DP4(p1a,W12,H4) DP4(p2a,W20,H4) DP4(p3a,W28,H4)
          DP4(p0b,W5,H5) DP4(p1b,W13,H5) DP4(p2b,W21,H5) DP4(p3b,W29,H5)
          DP4(p0a,W6,H6) DP4(p1a,W14,H6) DP4(p2a,W22,H6) DP4(p3a,W30,H6)
          DP4(p0b,W7,H7) DP4(p1b,W15,H7) DP4(p2b,W23,H7) DP4(p3b,W31,H7)
          f4 v;
          v.x = (p0a + p0b) + bb0;
          v.y = (p1a + p1b) + bb1;
          v.z = (p2a + p2b) + bb2;
          v.w = (p3a + p3b) + bb3;
          *(f4*)(xpf + slot * 256 + e * 4) = v;        // one ds_write_b128
        }
      }
      if (k >= 3) {                                    // head for block k-3
        const int base = (k - 3) * B;
        #pragma unroll 1
        for (int i = 0; i < B; ++i) {
          const int t = base + i;
          const int slot = t & (RS - 1);
          const u4* h1p = (const u4*)(h1r + slot * 32 + kq * 8);
          u4 X0 = h1p[0], X1 = h1p[1];
          float r2 = 0.f;
          DP4(r2, HW0, X0) DP4(r2, HW1, X1)
          r2 += DPPX1(r2);
          r2 += DPPX2(r2);                             // sum over kq (quad)
          if (kq == 0) out[t * 16 + m] = r2 + bl;
        }
      }
      BARRIER();
    }
  } else {
    // ============ wave2: layer-1 recurrence (block k-2), in-lane ============
    __builtin_amdgcn_s_setprio(1);
    const int e = tid - 128;
    const u4* wp = (const u4*)(ws + 8192 + e * 128);
    DECLW32(wp);
    float c1 = 0.f;
    _Float16* h1h = (_Float16*)h1r;

    for (int k = 0; k < K_SS; ++k) {
      if (k >= 2 && k <= NB + 1) {
        const int base = (k - 2) * B;
        #pragma unroll 1
        for (int i = 0; i < B; ++i) {
          const int t = base + i;
          const int slot = t & (RS - 1);
          PINALL();
          const f4 xq = *(const f4*)(xpf + slot * 256 + e * 4);  // hoisted b128
          const u4* hp = (const u4*)(h1r + ((t - 1) & (RS - 1)) * 32);
          u4 H0=hp[0],H1=hp[1],H2=hp[2],H3=hp[3],H4=hp[4],H5=hp[5],H6=hp[6],H7=hp[7];
          h2v ai0={0,0},ai1={0,0}, af0={0,0},af1={0,0},
              ag0={0,0},ag1={0,0}, ao0={0,0},ao1={0,0};
          DP4H(ai0,W0,H0)  DP4H(af0,W8,H0)  DP4H(ag0,W16,H0) DP4H(ao0,W24,H0)
          DP4H(ai1,W1,H1)  DP4H(af1,W9,H1)  DP4H(ag1,W17,H1) DP4H(ao1,W25,H1)
          DP4H(ai0,W2,H2)  DP4H(af0,W10,H2) DP4H(ag0,W18,H2) DP4H(ao0,W26,H2)
          DP4H(ai1,W3,H3)  DP4H(af1,W11,H3) DP4H(ag1,W19,H3) DP4H(ao1,W27,H3)
          DP4H(ai0,W4,H4)  DP4H(af0,W12,H4) DP4H(ag0,W20,H4) DP4H(ao0,W28,H4)
          DP4H(ai1,W5,H5)  DP4H(af1,W13,H5) DP4H(ag1,W21,H5) DP4H(ao1,W29,H5)
          DP4H(ai0,W6,H6)  DP4H(af0,W14,H6) DP4H(ag0,W22,H6) DP4H(ao0,W30,H6)
          DP4H(ai1,W7,H7)  DP4H(af1,W15,H7) DP4H(ag1,W23,H7) DP4H(ao1,W31,H7)
          float I = sig_u(fd(__builtin_bit_cast(unsigned, ai0 + ai1), ONES2, xq.x));
          float F = sig_u(fd(__builtin_bit_cast(unsigned, af0 + af1), ONES2, xq.y));
          float G = tanh_u(fd(__builtin_bit_cast(unsigned, ag0 + ag1), ONES2, xq.z));
          float O = sig_u(fd(__builtin_bit_cast(unsigned, ao0 + ao1), ONES2, xq.w));
          c1 = fmaf(F, c1, I * G);
          float h = O * tanh_c(c1);
          h1h[slot * 64 + e] = (_Float16)h;            // ds_write_b16
        }
      }
      BARRIER();
    }
  }
}

extern "C" void kernel_launch(void* const* d_in, const int* in_sizes, int n_in,
                              void* d_out, int out_size, void* d_ws, size_t ws_size,
                              hipStream_t stream) {
  const float* y    = (const float*)d_in[0];
  const float* Wih0 = (const float*)d_in[1];
  const float* Whh0 = (const float*)d_in[2];
  const float* bih0 = (const float*)d_in[3];
  const float* bhh0 = (const float*)d_in[4];
  const float* Wih1 = (const float*)d_in[5];
  const float* Whh1 = (const float*)d_in[6];
  const float* bih1 = (const float*)d_in[7];
  const float* bhh1 = (const float*)d_in[8];
  const float* Wlin = (const float*)d_in[9];
  const float* blin = (const float*)d_in[10];
  unsigned* ws = (unsigned*)d_ws;                // 25088 dwords ~= 100 KB

  pack_w<<<dim3(98), dim3(256), 0, stream>>>(Whh0, Whh1, Wih1, Wlin, ws);
  rnn_fused<<<dim3(1), dim3(192), 0, stream>>>(
      y, Wih0, bih0, bhh0, bih1, bhh1, blin, ws, (float*)d_out);
}